// Round 13
// baseline (213.957 us; speedup 1.0000x reference)
//
#include <hip/hip_runtime.h>
#include <hip/hip_bf16.h>

typedef unsigned short ushort_t;
typedef __bf16 bf16x8 __attribute__((ext_vector_type(8)));
typedef unsigned short us8 __attribute__((ext_vector_type(8)));
typedef float f32x4 __attribute__((ext_vector_type(4)));

__device__ __forceinline__ ushort_t f2b(float f) {
    union { float f; unsigned int u; } v; v.f = f;
    unsigned int u = v.u;
    unsigned int r = (u + 0x7FFFu + ((u >> 16) & 1u)) >> 16;
    return (ushort_t)r;
}
__device__ __forceinline__ float sigmoidf_(float x) {
    return 1.f / (1.f + __expf(-x));
}
__device__ __forceinline__ void store_o(ushort_t* p, float v) { *p = f2b(v); }
__device__ __forceinline__ void store_o(float* p, float v) { *p = v; }

__global__ void fill_kernel(float* out, long long n, float val) {
    long long i = (long long)blockIdx.x * blockDim.x + threadIdx.x;
    if (i < n) out[i] = val;
}

// ---------------------------------------------------------------------------
// Packed B layout for mfma_f32_16x16x32_bf16 (per 64-col block c, 32-k group
// kk): 4 col-subtiles su, 64 lanes (lane = k-oct*16 + col&15), 8 bf16.
// Tile (c,kk) = 2048 ushorts; wave fragment load = 1 KB contiguous.
// ---------------------------------------------------------------------------
#define PACKSZ(O, K) ((long long)((O) >= 64 ? (O) >> 6 : 1) * ((K) >> 5) * 2048)

// ---------------------------------------------------------------------------
// Prep work items (weights; perm-independent).
// ---------------------------------------------------------------------------
__device__ __forceinline__ void maskw_item(const float* __restrict__ alpha,
                                           const float* __restrict__ w,
                                           ushort_t* __restrict__ wm,
                                           long long idx, int O, int G, int dup) {
    int g = (int)(idx % G);
    long long t2 = idx / G;
    int o = (int)(t2 % O);
    int a = (int)(t2 / O);
    const float* al = alpha + idx * 6;
    float p[6];
    float mx = -1e30f;
    #pragma unroll
    for (int i = 0; i < 6; i++) { p[i] = al[i] * 0.2f; mx = fmaxf(mx, p[i]); }
    float s = 0.f;
    #pragma unroll
    for (int i = 0; i < 6; i++) { p[i] = __expf(p[i] - mx); s += p[i]; }
    float inv = 1.f / s;
    #pragma unroll
    for (int i = 0; i < 6; i++) p[i] *= inv;
    float mk[4] = { p[0] + p[1] + p[2], p[0] + p[3] + p[4],
                    p[1] + p[3] + p[5], p[2] + p[4] + p[5] };
    int K = G * 4;
    const float* wr = w + (long long)o * K + g * 4;
    ushort_t* base = wm + (long long)a * PACKSZ(O, K);
    int k0 = g * 4;
    int c = o >> 6, su = (o >> 4) & 3, n = o & 15;
    int kk = k0 >> 5, q = (k0 >> 3) & 3, e0 = k0 & 7;
    long long off = (((long long)(c * (K >> 5) + kk) * 4 + su) * 64 + (q * 16 + n)) * 8 + e0;
    #pragma unroll
    for (int t = 0; t < 4; t++) {
        ushort_t v = f2b(wr[t] * mk[t]);
        base[off + t] = v;
        if (dup) {
            base[off + t + 512] = v;
            base[off + t + 1024] = v;
            base[off + t + 1536] = v;
        }
    }
}

__device__ __forceinline__ void canon_pack_item(const float* __restrict__ src,
                                                ushort_t* __restrict__ dst,
                                                long long i) {
    long long base = i * 8;
    int o_full = (int)(base >> 9);
    int k0 = (int)(base & 511);
    int g = o_full >> 9, o = o_full & 511;
    int c = o >> 6, su = (o >> 4) & 3, n = o & 15;
    int kk = k0 >> 5, q = (k0 >> 3) & 3;
    long long off = (long long)g * 262144 +
        (((long long)(c * 16 + kk) * 4 + su) * 64 + (q * 16 + n)) * 8;
    us8 v;
    #pragma unroll
    for (int e = 0; e < 8; e++) v[e] = f2b(src[base + e]);
    *(us8*)(dst + off) = v;
}

__device__ __forceinline__ void canon_gather_item(const float* __restrict__ src,
                                                  ushort_t* __restrict__ dst,
                                                  const int* __restrict__ perm,
                                                  int ld, long long i) {
    long long base = i * 8;
    int pos = (int)(base / ld);
    int k = (int)(base % ld);
    int row = perm[pos] & 8191;
    const float* s = src + (long long)row * ld + k;
    us8 v;
    #pragma unroll
    for (int e = 0; e < 8; e++) v[e] = f2b(s[e]);
    *(us8*)(dst + base) = v;
}

// item-count boundaries in the weight-pack space (1024-thr blocks)
#define W_FC1 65536LL
#define W_FC2 589824LL
#define W_FC3 1114112LL
#define W_FC4 1130496LL
#define W_WIH 1228800LL
#define W_END 1327104LL
#define SPW_BLOCKS (1 + 1296)

// ---------------------------------------------------------------------------
// Merged kernel: block 0 = ballot sort (serial part, runs concurrently with
// the 1296 weight-packing blocks on other CUs). Weight packing is
// perm-independent; gathers run in a second kernel.
// ---------------------------------------------------------------------------
__global__ void sort_prepw(const int* __restrict__ ids,
                           int* __restrict__ perm, int* __restrict__ seg,
                           int4* __restrict__ ttab, int* __restrict__ tcount,
                           const float* fc1_al, const float* fc1_w, ushort_t* wm1,
                           const float* fc2_al, const float* fc2_w, ushort_t* wm2,
                           const float* fc3_al, const float* fc3_w, ushort_t* wm3,
                           const float* fc4_al, const float* fc4_w, ushort_t* wm4,
                           const float* wih, ushort_t* wihp,
                           const float* whh, ushort_t* whhp) {
    int tid = threadIdx.x;
    if (blockIdx.x == 0) {
        __shared__ int hist[16][8];
        __shared__ int wbase[16][8];
        __shared__ int atot[8];
        __shared__ int abase[8];
        int wave = tid >> 6, lane = tid & 63;
        int base = wave * 512;
        unsigned long long lt = (lane == 63) ? 0x7fffffffffffffffull
                                             : ((1ull << lane) - 1ull);
        int myid[8], rank[8];
        int run[8] = {0, 0, 0, 0, 0, 0, 0, 0};
        #pragma unroll
        for (int i = 0; i < 8; i++) myid[i] = ids[base + i * 64 + lane] & 7;
        #pragma unroll
        for (int i = 0; i < 8; i++) {
            int a = myid[i];
            int r = 0;
            #pragma unroll
            for (int a2 = 0; a2 < 8; a2++) {
                unsigned long long m = __ballot(a == a2);
                if (a2 == a) r = run[a2] + __popcll(m & lt);
                run[a2] += __popcll(m);
            }
            rank[i] = r;
        }
        if (lane == 0) {
            #pragma unroll
            for (int a = 0; a < 8; a++) hist[wave][a] = run[a];
        }
        __syncthreads();
        if (tid < 8) {
            int a = tid, s = 0;
            for (int w = 0; w < 16; w++) { wbase[w][a] = s; s += hist[w][a]; }
            atot[a] = s;
        }
        __syncthreads();
        if (tid == 0) {
            int s = 0;
            for (int a = 0; a < 8; a++) { abase[a] = s; seg[a] = s; s += atot[a]; }
            seg[8] = s;
            int T = 0;
            for (int a = 0; a < 8; a++)
                for (int m = abase[a]; m < abase[a] + atot[a]; m += 64) {
                    int e = abase[a] + atot[a];
                    if (e > m + 64) e = m + 64;
                    ttab[T++] = make_int4(a, m, e, 0);
                }
            *tcount = T;
        }
        __syncthreads();
        #pragma unroll
        for (int i = 0; i < 8; i++) {
            int a = myid[i];
            perm[abase[a] + wbase[wave][a] + rank[i]] = base + i * 64 + lane;
        }
        return;
    }
    long long gid = (long long)(blockIdx.x - 1) * 1024 + tid;
    if (gid < W_FC1)      { maskw_item(fc1_al, fc1_w, wm1, gid, 512, 16, 0); return; }
    if (gid < W_FC2)      { maskw_item(fc2_al, fc2_w, wm2, gid - W_FC1, 512, 128, 0); return; }
    if (gid < W_FC3)      { maskw_item(fc3_al, fc3_w, wm3, gid - W_FC2, 512, 128, 0); return; }
    if (gid < W_FC4)      { maskw_item(fc4_al, fc4_w, wm4, gid - W_FC3, 16, 128, 1); return; }
    if (gid < W_WIH)      { canon_pack_item(wih, wihp, gid - W_FC4); return; }
    canon_pack_item(whh, whhp, gid - W_WIH);
}

// gathers (perm-dependent): inp 65536 us8 items + hid 524288 us8 items
#define G_INP 65536LL
#define G_END 589824LL
#define PG_BLOCKS 576

__global__ void prep_gather(const float* __restrict__ inputs, ushort_t* inp_pos,
                            const float* __restrict__ hidden, ushort_t* hid_pos,
                            const int* __restrict__ perm) {
    long long gid = (long long)blockIdx.x * 1024 + threadIdx.x;
    if (gid < G_INP) canon_gather_item(inputs, inp_pos, perm, 64, gid);
    else             canon_gather_item(hidden, hid_pos, perm, 512, gid - G_INP);
}

// ---------------------------------------------------------------------------
// GEMM: R8 structure (proven): 2-kk unrolled, 8 MFMA per barrier-pair.
// A staged via swizzled LDS (2 buffers); B streamed from packed global.
// ---------------------------------------------------------------------------
#define BM 64
#define BN 64

template <typename OT>
__launch_bounds__(256, 4)
__global__ void gemm_tiled(const ushort_t* __restrict__ In, int ldin,
                           const ushort_t* __restrict__ Wpk, long long wstride,
                           const float* __restrict__ bias,
                           OT* __restrict__ Out, int ldo,
                           const int4* __restrict__ ttab,
                           const int* __restrict__ tcount,
                           const int* __restrict__ scatter,
                           int O, int K, int relu) {
    int t = blockIdx.x;
    if (t >= *tcount) return;
    int4 tt = ttab[t];
    int a = tt.x, pos0 = tt.y, pos1 = tt.z;
    int o0 = blockIdx.y * BN;

    __shared__ ushort_t As[2][2048];

    int tid = threadIdx.x;
    int wave = tid >> 6, lane = tid & 63;
    int wr = (wave >> 1) & 1, wc = wave & 1;
    int quad = lane >> 4, l16 = lane & 15;
    int srow = tid >> 2, sgrp = tid & 3;
    int wsoff = (srow * 4 + (sgrp ^ ((srow >> 2) & 3))) * 8;
    int rl = (l16 * 4 + (quad ^ ((l16 >> 2) & 3))) * 8;

    int apos = pos0 + srow;
    int apos_c = apos < pos1 ? apos : (pos1 - 1);
    const ushort_t* aptr = In + (long long)apos_c * ldin + sgrp * 8;

    const ushort_t* wb = Wpk + (long long)a * wstride +
        (long long)blockIdx.y * (K >> 5) * 2048 + lane * 8;

    f32x4 acc[2][2];
    #pragma unroll
    for (int i = 0; i < 2; i++)
        #pragma unroll
        for (int j = 0; j < 2; j++) acc[i][j] = (f32x4){0.f, 0.f, 0.f, 0.f};

    int KKh = K >> 6;    // pairs of 32-k groups
    for (int k2 = 0; k2 < KKh; k2++) {
        int kk = k2 * 2;
        us8 av0 = *(const us8*)(aptr + kk * 32);
        us8 av1 = *(const us8*)(aptr + kk * 32 + 32);
        bf16x8 b00 = *(const bf16x8*)(wb + (kk * 4 + wc * 2 + 0) * 512);
        bf16x8 b01 = *(const bf16x8*)(wb + (kk * 4 + wc * 2 + 1) * 512);
        bf16x8 b10 = *(const bf16x8*)(wb + ((kk + 1) * 4 + wc * 2 + 0) * 512);
        bf16x8 b11 = *(const bf16x8*)(wb + ((kk + 1) * 4 + wc * 2 + 1) * 512);
        __syncthreads();
        *(us8*)(&As[0][wsoff]) = av0;
        *(us8*)(&As[1][wsoff]) = av1;
        __syncthreads();
        bf16x8 af0[2], af1[2];
        af0[0] = *(const bf16x8*)(&As[0][(wr * 2 + 0) * 512 + rl]);
        af0[1] = *(const bf16x8*)(&As[0][(wr * 2 + 1) * 512 + rl]);
        af1[0] = *(const bf16x8*)(&As[1][(wr * 2 + 0) * 512 + rl]);
        af1[1] = *(const bf16x8*)(&As[1][(wr * 2 + 1) * 512 + rl]);
        #pragma unroll
        for (int i = 0; i < 2; i++) {
            acc[i][0] = __builtin_amdgcn_mfma_f32_16x16x32_bf16(af0[i], b00, acc[i][0], 0, 0, 0);
            acc[i][1] = __builtin_amdgcn_mfma_f32_16x16x32_bf16(af0[i], b01, acc[i][1], 0, 0, 0);
        }
        #pragma unroll
        for (int i = 0; i < 2; i++) {
            acc[i][0] = __builtin_amdgcn_mfma_f32_16x16x32_bf16(af1[i], b10, acc[i][0], 0, 0, 0);
            acc[i][1] = __builtin_amdgcn_mfma_f32_16x16x32_bf16(af1[i], b11, acc[i][1], 0, 0, 0);
        }
    }

    #pragma unroll
    for (int i = 0; i < 2; i++) {
        int mbase = wr * 32 + i * 16 + quad * 4;
        #pragma unroll
        for (int j = 0; j < 2; j++) {
            int col = o0 + wc * 32 + j * 16 + l16;
            if (col < O) {
                float bias_v = bias ? bias[col] : 0.f;
                #pragma unroll
                for (int r = 0; r < 4; r++) {
                    int pos = pos0 + mbase + r;
                    if (pos < pos1) {
                        float v = acc[i][j][r] + bias_v;
                        if (relu) v = fmaxf(v, 0.f);
                        int orow = (scatter ? scatter[pos] : pos) & 8191;
                        store_o(&Out[(long long)orow * ldo + col], v);
                    }
                }
            }
        }
    }
}

// ---------------------------------------------------------------------------
// Fused GRU, BM=128 (R8/R11 proven 42 us): A staged via swizzled LDS,
// B staged LDS shared by all waves; 2-barrier K-loop, 1-kk.
//   acc0 = y1.wih_r + h.whh_r ; acc1 = y1.wih_z + h.whh_z
//   acc2 = y1.wih_n           ; acc3 = h.whh_n
// ---------------------------------------------------------------------------
__launch_bounds__(512, 2)
__global__ void gru_fused(const ushort_t* __restrict__ y1,       // [N,H] pos bf16
                          const ushort_t* __restrict__ hid_pos,  // [N,H] pos bf16
                          const float* __restrict__ hidden_f,    // [N,H] orig fp32
                          const ushort_t* __restrict__ wihp,     // packed 3x(512,512)
                          const ushort_t* __restrict__ whhp,     // packed 3x(512,512)
                          const float* __restrict__ bih,
                          const float* __restrict__ bhh,
                          const int* __restrict__ perm,
                          float* __restrict__ out_h_f,           // [N,H] orig fp32
                          ushort_t* __restrict__ hp,             // [N,H] pos bf16
                          int N, int H) {
    int m0 = blockIdx.x * 128;

    __shared__ ushort_t Ay[4096];
    __shared__ ushort_t Ah[4096];
    __shared__ ushort_t Bt[6][2048];

    int tid = threadIdx.x;
    int wave = tid >> 6, lane = tid & 63;
    int wr = wave >> 1, wc = wave & 1;          // wr 0..3, wc 0..1
    int quad = lane >> 4, l16 = lane & 15;
    int srow = tid >> 2, sgrp = tid & 3;        // srow 0..127
    int wsoff = (srow * 4 + (sgrp ^ ((srow >> 2) & 3))) * 8;
    int rl = (l16 * 4 + (quad ^ ((l16 >> 2) & 3))) * 8;

    const ushort_t* ay_p = y1 + (long long)(m0 + srow) * H + sgrp * 8;
    const ushort_t* ah_p = hid_pos + (long long)(m0 + srow) * H + sgrp * 8;

    // B staging: 1536 us8 slots (6 tiles x 256), 3 per thread: s = q*512+tid
    const ushort_t* wbs[3];
    int wg[3];
    #pragma unroll
    for (int q = 0; q < 3; q++) {
        int s = q * 512 + tid;
        int g = s >> 8, so = s & 255;
        wg[q] = s;
        wbs[q] = ((g < 3) ? (wihp + (long long)g * 262144)
                          : (whhp + (long long)(g - 3) * 262144)) +
                 (long long)blockIdx.y * 16 * 2048 + so * 8;
    }

    f32x4 acc[4][2][2];
    #pragma unroll
    for (int g = 0; g < 4; g++)
        #pragma unroll
        for (int i = 0; i < 2; i++)
            #pragma unroll
            for (int j = 0; j < 2; j++) acc[g][i][j] = (f32x4){0.f, 0.f, 0.f, 0.f};

    for (int kk = 0; kk < 16; kk++) {
        us8 va = *(const us8*)(ay_p + kk * 32);
        us8 vh = *(const us8*)(ah_p + kk * 32);
        us8 vb[3];
        #pragma unroll
        for (int q = 0; q < 3; q++) vb[q] = *(const us8*)(wbs[q] + kk * 2048);
        __syncthreads();
        *(us8*)(&Ay[wsoff]) = va;
        *(us8*)(&Ah[wsoff]) = vh;
        #pragma unroll
        for (int q = 0; q < 3; q++) {
            int s = wg[q];
            *(us8*)(&Bt[s >> 8][(s & 255) * 8]) = vb[q];
        }
        __syncthreads();

        bf16x8 ayf[2], ahf[2];
        #pragma unroll
        for (int u = 0; u < 2; u++) {
            ayf[u] = *(const bf16x8*)(&Ay[(wr * 2 + u) * 512 + rl]);
            ahf[u] = *(const bf16x8*)(&Ah[(wr * 2 + u) * 512 + rl]);
        }
        #pragma unroll
        for (int g = 0; g < 3; g++) {
            bf16x8 bw[2], bu[2];
            #pragma unroll
            for (int u = 0; u < 2; u++) {
                bw[u] = *(const bf16x8*)(&Bt[g][(wc * 2 + u) * 512 + lane * 8]);
                bu[u] = *(const bf16x8*)(&Bt[g + 3][(wc * 2 + u) * 512 + lane * 8]);
            }
            int ai = (g < 2) ? g : 2;   // ih products: r->0, z->1, n->2
            int ah2 = (g < 2) ? g : 3;  // hh products: r->0, z->1, n->3
            #pragma unroll
            for (int i = 0; i < 2; i++)
                #pragma unroll
                for (int j = 0; j < 2; j++) {
                    acc[ai][i][j] = __builtin_amdgcn_mfma_f32_16x16x32_bf16(
                        ayf[i], bw[j], acc[ai][i][j], 0, 0, 0);
                    acc[ah2][i][j] = __builtin_amdgcn_mfma_f32_16x16x32_bf16(
                        ahf[i], bu[j], acc[ah2][i][j], 0, 0, 0);
                }
        }
    }

    int c0 = blockIdx.y * 64;
    #pragma unroll
    for (int i = 0; i < 2; i++) {
        #pragma unroll
        for (int r = 0; r < 4; r++) {
            int pos = m0 + wr * 32 + i * 16 + quad * 4 + r;
            int norig = perm[pos] & 8191;
            #pragma unroll
            for (int j = 0; j < 2; j++) {
                int col = c0 + wc * 32 + j * 16 + l16;
                float sr = acc[0][i][j][r] + bih[col] + bhh[col];
                float sz = acc[1][i][j][r] + bih[H + col] + bhh[H + col];
                float in_ = acc[2][i][j][r] + bih[2 * H + col];
                float hn = acc[3][i][j][r] + bhh[2 * H + col];
                float rg = sigmoidf_(sr);
                float zg = sigmoidf_(sz);
                float ng = tanhf(in_ + rg * hn);
                float hv = hidden_f[(long long)norig * H + col];
                float hnew = (1.f - zg) * ng + zg * hv;
                out_h_f[(long long)norig * H + col] = hnew;
                hp[(long long)pos * H + col] = f2b(hnew);
            }
        }
    }
}

// ---------------------------------------------------------------------------
extern "C" void kernel_launch(void* const* d_in, const int* in_sizes, int n_in,
                              void* d_out, int out_size, void* d_ws, size_t ws_size,
                              hipStream_t stream) {
    (void)in_sizes; (void)n_in;
    const int N = 8192, A = 8, E = 64, H = 512, NA = 16;

    float* out_f = (float*)d_out;
    float* out_q = out_f;                        // [N, NA] fp32
    float* out_h = out_f + (size_t)N * NA;       // [N, H] fp32, original order

    char* p = (char*)d_ws;
    auto alloc = [&](size_t b) { char* r = p; p += (b + 255) & ~(size_t)255; return r; };
    int*  perm   = (int*)alloc((size_t)N * 4);
    int*  seg    = (int*)alloc(16 * 4);
    int4* ttab   = (int4*)alloc(144 * 16);
    int*  tcount = (int*)alloc(256);
    ushort_t* wm1     = (ushort_t*)alloc((size_t)A * PACKSZ(H, E) * 2);
    ushort_t* wm2     = (ushort_t*)alloc((size_t)A * PACKSZ(H, H) * 2);
    ushort_t* wm3     = (ushort_t*)alloc((size_t)A * PACKSZ(H, H) * 2);
    ushort_t* wm4     = (ushort_t*)alloc((size_t)A * PACKSZ(NA, H) * 2);
    ushort_t* y1      = (ushort_t*)alloc((size_t)N * H * 2);
    ushort_t* inp_pos = (ushort_t*)alloc((size_t)N * E * 2);
    ushort_t* hid_pos = (ushort_t*)alloc((size_t)N * H * 2);
    ushort_t* wihp    = (ushort_t*)alloc((size_t)3 * H * H * 2);
    ushort_t* whhp    = (ushort_t*)alloc((size_t)3 * H * H * 2);
    ushort_t* hp      = (ushort_t*)alloc((size_t)N * H * 2);
    size_t need = (size_t)(p - (char*)d_ws);
    ushort_t* q2 = y1;       // alias: y1 dead after gru_fused
    ushort_t* q3 = hid_pos;  // alias: hid_pos dead after gru_fused

    if (ws_size < need) {
        fill_kernel<<<(unsigned)((out_size + 255) / 256), 256, 0, stream>>>(
            out_f, out_size, 1000.f);
        return;
    }

    const float* inputs = (const float*)d_in[0];
    const float* hidden = (const float*)d_in[1];
    const int*   ids    = (const int*)d_in[2];
    const float* fc1_w  = (const float*)d_in[3];
    const float* fc1_b  = (const float*)d_in[4];
    const float* fc1_al = (const float*)d_in[5];
    const float* wih    = (const float*)d_in[6];
    const float* whh    = (const float*)d_in[7];
    const float* bih    = (const float*)d_in[8];
    const float* bhh    = (const float*)d_in[9];
    const float* fc2_w  = (const float*)d_in[10];
    const float* fc2_b  = (const float*)d_in[11];
    const float* fc2_al = (const float*)d_in[12];
    const float* fc3_w  = (const float*)d_in[13];
    const float* fc3_b  = (const float*)d_in[14];
    const float* fc3_al = (const float*)d_in[15];
    const float* fc4_w  = (const float*)d_in[16];
    const float* fc4_b  = (const float*)d_in[17];
    const float* fc4_al = (const float*)d_in[18];

    sort_prepw<<<SPW_BLOCKS, 1024, 0, stream>>>(
        ids, perm, seg, ttab, tcount,
        fc1_al, fc1_w, wm1, fc2_al, fc2_w, wm2, fc3_al, fc3_w, wm3,
        fc4_al, fc4_w, wm4, wih, wihp, whh, whhp);

    prep_gather<<<PG_BLOCKS, 1024, 0, stream>>>(
        inputs, inp_pos, hidden, hid_pos, perm);

    dim3 blk(256);
    gemm_tiled<ushort_t><<<dim3(136, H / BN), blk, 0, stream>>>(
        inp_pos, E, wm1, PACKSZ(H, E), fc1_b, y1, H, ttab, tcount,
        nullptr, H, E, 1);
    gru_fused<<<dim3(N / 128, H / 64), dim3(512), 0, stream>>>(
        y1, hid_pos, hidden, wihp, whhp, bih, bhh, perm, out_h, hp, N, H);
    gemm_tiled<ushort_t><<<dim3(136, H / BN), blk, 0, stream>>>(
        hp, H, wm2, PACKSZ(H, H), fc2_b, q2, H, ttab, tcount,
        nullptr, H, H, 1);
    gemm_tiled<ushort_t><<<dim3(136, H / BN), blk, 0, stream>>>(
        q2, H, wm3, PACKSZ(H, H), fc3_b, q3, H, ttab, tcount,
        nullptr, H, H, 1);
    gemm_tiled<float><<<dim3(136, 1), blk, 0, stream>>>(
        q3, H, wm4, PACKSZ(NA, H), fc4_b, out_q, NA, ttab, tcount,
        perm, NA, H, 0);
}

// Round 14
// 208.752 us; speedup vs baseline: 1.0249x; 1.0249x over previous
//
#include <hip/hip_runtime.h>
#include <hip/hip_bf16.h>

typedef unsigned short ushort_t;
typedef __bf16 bf16x8 __attribute__((ext_vector_type(8)));
typedef unsigned short us8 __attribute__((ext_vector_type(8)));
typedef float f32x4 __attribute__((ext_vector_type(4)));

__device__ __forceinline__ ushort_t f2b(float f) {
    union { float f; unsigned int u; } v; v.f = f;
    unsigned int u = v.u;
    unsigned int r = (u + 0x7FFFu + ((u >> 16) & 1u)) >> 16;
    return (ushort_t)r;
}
__device__ __forceinline__ float sigmoidf_(float x) {
    return 1.f / (1.f + __expf(-x));
}
__device__ __forceinline__ void store_o(ushort_t* p, float v) { *p = f2b(v); }
__device__ __forceinline__ void store_o(float* p, float v) { *p = v; }

__global__ void fill_kernel(float* out, long long n, float val) {
    long long i = (long long)blockIdx.x * blockDim.x + threadIdx.x;
    if (i < n) out[i] = val;
}

// ---------------------------------------------------------------------------
// Packed B layout for mfma_f32_16x16x32_bf16 (per 64-col block c, 32-k group
// kk): 4 col-subtiles su, 64 lanes (lane = k-oct*16 + col&15), 8 bf16.
// Tile (c,kk) = 2048 ushorts; wave fragment load = 1 KB contiguous.
// ---------------------------------------------------------------------------
#define PACKSZ(O, K) ((long long)((O) >= 64 ? (O) >> 6 : 1) * ((K) >> 5) * 2048)

// ---------------------------------------------------------------------------
// Prep work items (weights; perm-independent).
// ---------------------------------------------------------------------------
__device__ __forceinline__ void maskw_item(const float* __restrict__ alpha,
                                           const float* __restrict__ w,
                                           ushort_t* __restrict__ wm,
                                           long long idx, int O, int G, int dup) {
    int g = (int)(idx % G);
    long long t2 = idx / G;
    int o = (int)(t2 % O);
    int a = (int)(t2 / O);
    const float* al = alpha + idx * 6;
    float p[6];
    float mx = -1e30f;
    #pragma unroll
    for (int i = 0; i < 6; i++) { p[i] = al[i] * 0.2f; mx = fmaxf(mx, p[i]); }
    float s = 0.f;
    #pragma unroll
    for (int i = 0; i < 6; i++) { p[i] = __expf(p[i] - mx); s += p[i]; }
    float inv = 1.f / s;
    #pragma unroll
    for (int i = 0; i < 6; i++) p[i] *= inv;
    float mk[4] = { p[0] + p[1] + p[2], p[0] + p[3] + p[4],
                    p[1] + p[3] + p[5], p[2] + p[4] + p[5] };
    int K = G * 4;
    const float* wr = w + (long long)o * K + g * 4;
    ushort_t* base = wm + (long long)a * PACKSZ(O, K);
    int k0 = g * 4;
    int c = o >> 6, su = (o >> 4) & 3, n = o & 15;
    int kk = k0 >> 5, q = (k0 >> 3) & 3, e0 = k0 & 7;
    long long off = (((long long)(c * (K >> 5) + kk) * 4 + su) * 64 + (q * 16 + n)) * 8 + e0;
    #pragma unroll
    for (int t = 0; t < 4; t++) {
        ushort_t v = f2b(wr[t] * mk[t]);
        base[off + t] = v;
        if (dup) {
            base[off + t + 512] = v;
            base[off + t + 1024] = v;
            base[off + t + 1536] = v;
        }
    }
}

__device__ __forceinline__ void canon_pack_item(const float* __restrict__ src,
                                                ushort_t* __restrict__ dst,
                                                long long i) {
    long long base = i * 8;
    int o_full = (int)(base >> 9);
    int k0 = (int)(base & 511);
    int g = o_full >> 9, o = o_full & 511;
    int c = o >> 6, su = (o >> 4) & 3, n = o & 15;
    int kk = k0 >> 5, q = (k0 >> 3) & 3;
    long long off = (long long)g * 262144 +
        (((long long)(c * 16 + kk) * 4 + su) * 64 + (q * 16 + n)) * 8;
    us8 v;
    #pragma unroll
    for (int e = 0; e < 8; e++) v[e] = f2b(src[base + e]);
    *(us8*)(dst + off) = v;
}

__device__ __forceinline__ void canon_gather_item(const float* __restrict__ src,
                                                  ushort_t* __restrict__ dst,
                                                  const int* __restrict__ perm,
                                                  int ld, long long i) {
    long long base = i * 8;
    int pos = (int)(base / ld);
    int k = (int)(base % ld);
    int row = perm[pos] & 8191;
    const float* s = src + (long long)row * ld + k;
    us8 v;
    #pragma unroll
    for (int e = 0; e < 8; e++) v[e] = f2b(s[e]);
    *(us8*)(dst + base) = v;
}

// item-count boundaries in the weight-pack space (1024-thr blocks)
#define W_FC1 65536LL
#define W_FC2 589824LL
#define W_FC3 1114112LL
#define W_FC4 1130496LL
#define W_WIH 1228800LL
#define W_END 1327104LL
#define SPW_BLOCKS (1 + 1296)

// ---------------------------------------------------------------------------
// Merged kernel: block 0 = ballot sort (serial part, runs concurrently with
// the 1296 weight-packing blocks on other CUs). Weight packing is
// perm-independent.
// ---------------------------------------------------------------------------
__global__ void sort_prepw(const int* __restrict__ ids,
                           int* __restrict__ perm, int* __restrict__ seg,
                           int4* __restrict__ ttab, int* __restrict__ tcount,
                           const float* fc1_al, const float* fc1_w, ushort_t* wm1,
                           const float* fc2_al, const float* fc2_w, ushort_t* wm2,
                           const float* fc3_al, const float* fc3_w, ushort_t* wm3,
                           const float* fc4_al, const float* fc4_w, ushort_t* wm4,
                           const float* wih, ushort_t* wihp,
                           const float* whh, ushort_t* whhp) {
    int tid = threadIdx.x;
    if (blockIdx.x == 0) {
        __shared__ int hist[16][8];
        __shared__ int wbase[16][8];
        __shared__ int atot[8];
        __shared__ int abase[8];
        int wave = tid >> 6, lane = tid & 63;
        int base = wave * 512;
        unsigned long long lt = (lane == 63) ? 0x7fffffffffffffffull
                                             : ((1ull << lane) - 1ull);
        int myid[8], rank[8];
        int run[8] = {0, 0, 0, 0, 0, 0, 0, 0};
        #pragma unroll
        for (int i = 0; i < 8; i++) myid[i] = ids[base + i * 64 + lane] & 7;
        #pragma unroll
        for (int i = 0; i < 8; i++) {
            int a = myid[i];
            int r = 0;
            #pragma unroll
            for (int a2 = 0; a2 < 8; a2++) {
                unsigned long long m = __ballot(a == a2);
                if (a2 == a) r = run[a2] + __popcll(m & lt);
                run[a2] += __popcll(m);
            }
            rank[i] = r;
        }
        if (lane == 0) {
            #pragma unroll
            for (int a = 0; a < 8; a++) hist[wave][a] = run[a];
        }
        __syncthreads();
        if (tid < 8) {
            int a = tid, s = 0;
            for (int w = 0; w < 16; w++) { wbase[w][a] = s; s += hist[w][a]; }
            atot[a] = s;
        }
        __syncthreads();
        if (tid == 0) {
            int s = 0;
            for (int a = 0; a < 8; a++) { abase[a] = s; seg[a] = s; s += atot[a]; }
            seg[8] = s;
            int T = 0;
            for (int a = 0; a < 8; a++)
                for (int m = abase[a]; m < abase[a] + atot[a]; m += 64) {
                    int e = abase[a] + atot[a];
                    if (e > m + 64) e = m + 64;
                    ttab[T++] = make_int4(a, m, e, 0);
                }
            *tcount = T;
        }
        __syncthreads();
        #pragma unroll
        for (int i = 0; i < 8; i++) {
            int a = myid[i];
            perm[abase[a] + wbase[wave][a] + rank[i]] = base + i * 64 + lane;
        }
        return;
    }
    long long gid = (long long)(blockIdx.x - 1) * 1024 + tid;
    if (gid < W_FC1)      { maskw_item(fc1_al, fc1_w, wm1, gid, 512, 16, 0); return; }
    if (gid < W_FC2)      { maskw_item(fc2_al, fc2_w, wm2, gid - W_FC1, 512, 128, 0); return; }
    if (gid < W_FC3)      { maskw_item(fc3_al, fc3_w, wm3, gid - W_FC2, 512, 128, 0); return; }
    if (gid < W_FC4)      { maskw_item(fc4_al, fc4_w, wm4, gid - W_FC3, 16, 128, 1); return; }
    if (gid < W_WIH)      { canon_pack_item(wih, wihp, gid - W_FC4); return; }
    canon_pack_item(whh, whhp, gid - W_WIH);
}

// ---------------------------------------------------------------------------
// fc1 GEMM + embedded hidden-gather. Compute blocks (x < 136): R8-structure
// GEMM with A gathered DIRECTLY from fp32 inputs via perm (K=64, one
// barrier-pair). Gather blocks (x >= 136): stage hidden -> hid_pos bf16
// pos-order (2048 blocks x 256 thr x 1 us8). Kernel boundary before
// gru_fused guarantees hid_pos completeness.
// ---------------------------------------------------------------------------
__launch_bounds__(256, 4)
__global__ void gemm_fc1(const float* __restrict__ inputs,    // [N,64] fp32
                         const ushort_t* __restrict__ Wpk,    // wm1
                         long long wstride,
                         const float* __restrict__ bias,
                         ushort_t* __restrict__ Out, int ldo, // y1 pos-order
                         const int4* __restrict__ ttab,
                         const int* __restrict__ tcount,
                         const int* __restrict__ perm,
                         const float* __restrict__ hidden,    // [N,512] fp32
                         ushort_t* __restrict__ hid_pos,
                         int O) {
    if (blockIdx.x >= 136) {
        long long idx = ((long long)(blockIdx.x - 136) * 8 + blockIdx.y) * 256
                        + threadIdx.x;
        canon_gather_item(hidden, hid_pos, perm, 512, idx);
        return;
    }
    int t = blockIdx.x;
    if (t >= *tcount) return;
    int4 tt = ttab[t];
    int a = tt.x, pos0 = tt.y, pos1 = tt.z;
    int o0 = blockIdx.y * 64;

    __shared__ ushort_t As[2][2048];

    int tid = threadIdx.x;
    int wave = tid >> 6, lane = tid & 63;
    int wr = (wave >> 1) & 1, wc = wave & 1;
    int quad = lane >> 4, l16 = lane & 15;
    int srow = tid >> 2, sgrp = tid & 3;
    int wsoff = (srow * 4 + (sgrp ^ ((srow >> 2) & 3))) * 8;
    int rl = (l16 * 4 + (quad ^ ((l16 >> 2) & 3))) * 8;

    int apos = pos0 + srow;
    int apos_c = apos < pos1 ? apos : (pos1 - 1);
    int arow = perm[apos_c] & 8191;
    const float* ap = inputs + (long long)arow * 64 + sgrp * 8;

    const ushort_t* wb = Wpk + (long long)a * wstride +
        (long long)blockIdx.y * 2 * 2048 + lane * 8;   // K=64 -> KK=2

    f32x4 acc[2][2];
    #pragma unroll
    for (int i = 0; i < 2; i++)
        #pragma unroll
        for (int j = 0; j < 2; j++) acc[i][j] = (f32x4){0.f, 0.f, 0.f, 0.f};

    // single 2-kk step (K = 64)
    us8 av0, av1;
    #pragma unroll
    for (int e = 0; e < 8; e++) {
        av0[e] = f2b(ap[e]);
        av1[e] = f2b(ap[32 + e]);
    }
    bf16x8 b00 = *(const bf16x8*)(wb + (0 * 4 + wc * 2 + 0) * 512);
    bf16x8 b01 = *(const bf16x8*)(wb + (0 * 4 + wc * 2 + 1) * 512);
    bf16x8 b10 = *(const bf16x8*)(wb + (1 * 4 + wc * 2 + 0) * 512);
    bf16x8 b11 = *(const bf16x8*)(wb + (1 * 4 + wc * 2 + 1) * 512);
    *(us8*)(&As[0][wsoff]) = av0;
    *(us8*)(&As[1][wsoff]) = av1;
    __syncthreads();
    bf16x8 af0[2], af1[2];
    af0[0] = *(const bf16x8*)(&As[0][(wr * 2 + 0) * 512 + rl]);
    af0[1] = *(const bf16x8*)(&As[0][(wr * 2 + 1) * 512 + rl]);
    af1[0] = *(const bf16x8*)(&As[1][(wr * 2 + 0) * 512 + rl]);
    af1[1] = *(const bf16x8*)(&As[1][(wr * 2 + 1) * 512 + rl]);
    #pragma unroll
    for (int i = 0; i < 2; i++) {
        acc[i][0] = __builtin_amdgcn_mfma_f32_16x16x32_bf16(af0[i], b00, acc[i][0], 0, 0, 0);
        acc[i][1] = __builtin_amdgcn_mfma_f32_16x16x32_bf16(af0[i], b01, acc[i][1], 0, 0, 0);
    }
    #pragma unroll
    for (int i = 0; i < 2; i++) {
        acc[i][0] = __builtin_amdgcn_mfma_f32_16x16x32_bf16(af1[i], b10, acc[i][0], 0, 0, 0);
        acc[i][1] = __builtin_amdgcn_mfma_f32_16x16x32_bf16(af1[i], b11, acc[i][1], 0, 0, 0);
    }

    #pragma unroll
    for (int i = 0; i < 2; i++) {
        int mbase = wr * 32 + i * 16 + quad * 4;
        #pragma unroll
        for (int j = 0; j < 2; j++) {
            int col = o0 + wc * 32 + j * 16 + l16;
            if (col < O) {
                float bias_v = bias[col];
                #pragma unroll
                for (int r = 0; r < 4; r++) {
                    int pos = pos0 + mbase + r;
                    if (pos < pos1) {
                        float v = fmaxf(acc[i][j][r] + bias_v, 0.f);
                        Out[(long long)pos * ldo + col] = f2b(v);
                    }
                }
            }
        }
    }
}

// ---------------------------------------------------------------------------
// GEMM: R8 structure (proven): 2-kk unrolled, 8 MFMA per barrier-pair.
// A staged via swizzled LDS (2 buffers); B streamed from packed global.
// ---------------------------------------------------------------------------
#define BM 64
#define BN 64

template <typename OT>
__launch_bounds__(256, 4)
__global__ void gemm_tiled(const ushort_t* __restrict__ In, int ldin,
                           const ushort_t* __restrict__ Wpk, long long wstride,
                           const float* __restrict__ bias,
                           OT* __restrict__ Out, int ldo,
                           const int4* __restrict__ ttab,
                           const int* __restrict__ tcount,
                           const int* __restrict__ scatter,
                           int O, int K, int relu) {
    int t = blockIdx.x;
    if (t >= *tcount) return;
    int4 tt = ttab[t];
    int a = tt.x, pos0 = tt.y, pos1 = tt.z;
    int o0 = blockIdx.y * BN;

    __shared__ ushort_t As[2][2048];

    int tid = threadIdx.x;
    int wave = tid >> 6, lane = tid & 63;
    int wr = (wave >> 1) & 1, wc = wave & 1;
    int quad = lane >> 4, l16 = lane & 15;
    int srow = tid >> 2, sgrp = tid & 3;
    int wsoff = (srow * 4 + (sgrp ^ ((srow >> 2) & 3))) * 8;
    int rl = (l16 * 4 + (quad ^ ((l16 >> 2) & 3))) * 8;

    int apos = pos0 + srow;
    int apos_c = apos < pos1 ? apos : (pos1 - 1);
    const ushort_t* aptr = In + (long long)apos_c * ldin + sgrp * 8;

    const ushort_t* wb = Wpk + (long long)a * wstride +
        (long long)blockIdx.y * (K >> 5) * 2048 + lane * 8;

    f32x4 acc[2][2];
    #pragma unroll
    for (int i = 0; i < 2; i++)
        #pragma unroll
        for (int j = 0; j < 2; j++) acc[i][j] = (f32x4){0.f, 0.f, 0.f, 0.f};

    int KKh = K >> 6;    // pairs of 32-k groups
    for (int k2 = 0; k2 < KKh; k2++) {
        int kk = k2 * 2;
        us8 av0 = *(const us8*)(aptr + kk * 32);
        us8 av1 = *(const us8*)(aptr + kk * 32 + 32);
        bf16x8 b00 = *(const bf16x8*)(wb + (kk * 4 + wc * 2 + 0) * 512);
        bf16x8 b01 = *(const bf16x8*)(wb + (kk * 4 + wc * 2 + 1) * 512);
        bf16x8 b10 = *(const bf16x8*)(wb + ((kk + 1) * 4 + wc * 2 + 0) * 512);
        bf16x8 b11 = *(const bf16x8*)(wb + ((kk + 1) * 4 + wc * 2 + 1) * 512);
        __syncthreads();
        *(us8*)(&As[0][wsoff]) = av0;
        *(us8*)(&As[1][wsoff]) = av1;
        __syncthreads();
        bf16x8 af0[2], af1[2];
        af0[0] = *(const bf16x8*)(&As[0][(wr * 2 + 0) * 512 + rl]);
        af0[1] = *(const bf16x8*)(&As[0][(wr * 2 + 1) * 512 + rl]);
        af1[0] = *(const bf16x8*)(&As[1][(wr * 2 + 0) * 512 + rl]);
        af1[1] = *(const bf16x8*)(&As[1][(wr * 2 + 1) * 512 + rl]);
        #pragma unroll
        for (int i = 0; i < 2; i++) {
            acc[i][0] = __builtin_amdgcn_mfma_f32_16x16x32_bf16(af0[i], b00, acc[i][0], 0, 0, 0);
            acc[i][1] = __builtin_amdgcn_mfma_f32_16x16x32_bf16(af0[i], b01, acc[i][1], 0, 0, 0);
        }
        #pragma unroll
        for (int i = 0; i < 2; i++) {
            acc[i][0] = __builtin_amdgcn_mfma_f32_16x16x32_bf16(af1[i], b10, acc[i][0], 0, 0, 0);
            acc[i][1] = __builtin_amdgcn_mfma_f32_16x16x32_bf16(af1[i], b11, acc[i][1], 0, 0, 0);
        }
    }

    #pragma unroll
    for (int i = 0; i < 2; i++) {
        int mbase = wr * 32 + i * 16 + quad * 4;
        #pragma unroll
        for (int j = 0; j < 2; j++) {
            int col = o0 + wc * 32 + j * 16 + l16;
            if (col < O) {
                float bias_v = bias ? bias[col] : 0.f;
                #pragma unroll
                for (int r = 0; r < 4; r++) {
                    int pos = pos0 + mbase + r;
                    if (pos < pos1) {
                        float v = acc[i][j][r] + bias_v;
                        if (relu) v = fmaxf(v, 0.f);
                        int orow = (scatter ? scatter[pos] : pos) & 8191;
                        store_o(&Out[(long long)orow * ldo + col], v);
                    }
                }
            }
        }
    }
}

// ---------------------------------------------------------------------------
// Fused GRU, BM=128 (R8/R11/R13 proven ~41-42 us): A staged via swizzled
// LDS, B staged LDS shared by all waves; 2-barrier K-loop, 1-kk.
//   acc0 = y1.wih_r + h.whh_r ; acc1 = y1.wih_z + h.whh_z
//   acc2 = y1.wih_n           ; acc3 = h.whh_n
// ---------------------------------------------------------------------------
__launch_bounds__(512, 2)
__global__ void gru_fused(const ushort_t* __restrict__ y1,       // [N,H] pos bf16
                          const ushort_t* __restrict__ hid_pos,  // [N,H] pos bf16
                          const float* __restrict__ hidden_f,    // [N,H] orig fp32
                          const ushort_t* __restrict__ wihp,     // packed 3x(512,512)
                          const ushort_t* __restrict__ whhp,     // packed 3x(512,512)
                          const float* __restrict__ bih,
                          const float* __restrict__ bhh,
                          const int* __restrict__ perm,
                          float* __restrict__ out_h_f,           // [N,H] orig fp32
                          ushort_t* __restrict__ hp,             // [N,H] pos bf16
                          int N, int H) {
    int m0 = blockIdx.x * 128;

    __shared__ ushort_t Ay[4096];
    __shared__ ushort_t Ah[4096];
    __shared__ ushort_t Bt[6][2048];

    int tid = threadIdx.x;
    int wave = tid >> 6, lane = tid & 63;
    int wr = wave >> 1, wc = wave & 1;          // wr 0..3, wc 0..1
    int quad = lane >> 4, l16 = lane & 15;
    int srow = tid >> 2, sgrp = tid & 3;        // srow 0..127
    int wsoff = (srow * 4 + (sgrp ^ ((srow >> 2) & 3))) * 8;
    int rl = (l16 * 4 + (quad ^ ((l16 >> 2) & 3))) * 8;

    const ushort_t* ay_p = y1 + (long long)(m0 + srow) * H + sgrp * 8;
    const ushort_t* ah_p = hid_pos + (long long)(m0 + srow) * H + sgrp * 8;

    // B staging: 1536 us8 slots (6 tiles x 256), 3 per thread: s = q*512+tid
    const ushort_t* wbs[3];
    int wg[3];
    #pragma unroll
    for (int q = 0; q < 3; q++) {
        int s = q * 512 + tid;
        int g = s >> 8, so = s & 255;
        wg[q] = s;
        wbs[q] = ((g < 3) ? (wihp + (long long)g * 262144)
                          : (whhp + (long long)(g - 3) * 262144)) +
                 (long long)blockIdx.y * 16 * 2048 + so * 8;
    }

    f32x4 acc[4][2][2];
    #pragma unroll
    for (int g = 0; g < 4; g++)
        #pragma unroll
        for (int i = 0; i < 2; i++)
            #pragma unroll
            for (int j = 0; j < 2; j++) acc[g][i][j] = (f32x4){0.f, 0.f, 0.f, 0.f};

    for (int kk = 0; kk < 16; kk++) {
        us8 va = *(const us8*)(ay_p + kk * 32);
        us8 vh = *(const us8*)(ah_p + kk * 32);
        us8 vb[3];
        #pragma unroll
        for (int q = 0; q < 3; q++) vb[q] = *(const us8*)(wbs[q] + kk * 2048);
        __syncthreads();
        *(us8*)(&Ay[wsoff]) = va;
        *(us8*)(&Ah[wsoff]) = vh;
        #pragma unroll
        for (int q = 0; q < 3; q++) {
            int s = wg[q];
            *(us8*)(&Bt[s >> 8][(s & 255) * 8]) = vb[q];
        }
        __syncthreads();

        bf16x8 ayf[2], ahf[2];
        #pragma unroll
        for (int u = 0; u < 2; u++) {
            ayf[u] = *(const bf16x8*)(&Ay[(wr * 2 + u) * 512 + rl]);
            ahf[u] = *(const bf16x8*)(&Ah[(wr * 2 + u) * 512 + rl]);
        }
        #pragma unroll
        for (int g = 0; g < 3; g++) {
            bf16x8 bw[2], bu[2];
            #pragma unroll
            for (int u = 0; u < 2; u++) {
                bw[u] = *(const bf16x8*)(&Bt[g][(wc * 2 + u) * 512 + lane * 8]);
                bu[u] = *(const bf16x8*)(&Bt[g + 3][(wc * 2 + u) * 512 + lane * 8]);
            }
            int ai = (g < 2) ? g : 2;   // ih products: r->0, z->1, n->2
            int ah2 = (g < 2) ? g : 3;  // hh products: r->0, z->1, n->3
            #pragma unroll
            for (int i = 0; i < 2; i++)
                #pragma unroll
                for (int j = 0; j < 2; j++) {
                    acc[ai][i][j] = __builtin_amdgcn_mfma_f32_16x16x32_bf16(
                        ayf[i], bw[j], acc[ai][i][j], 0, 0, 0);
                    acc[ah2][i][j] = __builtin_amdgcn_mfma_f32_16x16x32_bf16(
                        ahf[i], bu[j], acc[ah2][i][j], 0, 0, 0);
                }
        }
    }

    int c0 = blockIdx.y * 64;
    #pragma unroll
    for (int i = 0; i < 2; i++) {
        #pragma unroll
        for (int r = 0; r < 4; r++) {
            int pos = m0 + wr * 32 + i * 16 + quad * 4 + r;
            int norig = perm[pos] & 8191;
            #pragma unroll
            for (int j = 0; j < 2; j++) {
                int col = c0 + wc * 32 + j * 16 + l16;
                float sr = acc[0][i][j][r] + bih[col] + bhh[col];
                float sz = acc[1][i][j][r] + bih[H + col] + bhh[H + col];
                float in_ = acc[2][i][j][r] + bih[2 * H + col];
                float hn = acc[3][i][j][r] + bhh[2 * H + col];
                float rg = sigmoidf_(sr);
                float zg = sigmoidf_(sz);
                float ng = tanhf(in_ + rg * hn);
                float hv = hidden_f[(long long)norig * H + col];
                float hnew = (1.f - zg) * ng + zg * hv;
                out_h_f[(long long)norig * H + col] = hnew;
                hp[(long long)pos * H + col] = f2b(hnew);
            }
        }
    }
}

// ---------------------------------------------------------------------------
extern "C" void kernel_launch(void* const* d_in, const int* in_sizes, int n_in,
                              void* d_out, int out_size, void* d_ws, size_t ws_size,
                              hipStream_t stream) {
    (void)in_sizes; (void)n_in;
    const int N = 8192, A = 8, E = 64, H = 512, NA = 16;

    float* out_f = (float*)d_out;
    float* out_q = out_f;                        // [N, NA] fp32
    float* out_h = out_f + (size_t)N * NA;       // [N, H] fp32, original order

    char* p = (char*)d_ws;
    auto alloc = [&](size_t b) { char* r = p; p += (b + 255) & ~(size_t)255; return r; };
    int*  perm   = (int*)alloc((size_t)N * 4);
    int*  seg    = (int*)alloc(16 * 4);
    int4* ttab   = (int4*)alloc(144 * 16);
    int*  tcount = (int*)alloc(256);
    ushort_t* wm1     = (ushort_t*)alloc((size_t)A * PACKSZ(H, E) * 2);
    ushort_t* wm2     = (ushort_t*)alloc((size_t)A * PACKSZ(H, H) * 2);
    ushort_t* wm3     = (ushort_t*)alloc((size_t)A * PACKSZ(H, H) * 2);
    ushort_t* wm4     = (ushort_t*)alloc((size_t)A * PACKSZ(NA, H) * 2);
    ushort_t* y1      = (ushort_t*)alloc((size_t)N * H * 2);
    ushort_t* hid_pos = (ushort_t*)alloc((size_t)N * H * 2);
    ushort_t* wihp    = (ushort_t*)alloc((size_t)3 * H * H * 2);
    ushort_t* whhp    = (ushort_t*)alloc((size_t)3 * H * H * 2);
    ushort_t* hp      = (ushort_t*)alloc((size_t)N * H * 2);
    size_t need = (size_t)(p - (char*)d_ws);
    ushort_t* q2 = y1;       // alias: y1 dead after gru_fused
    ushort_t* q3 = hid_pos;  // alias: hid_pos dead after gru_fused

    if (ws_size < need) {
        fill_kernel<<<(unsigned)((out_size + 255) / 256), 256, 0, stream>>>(
            out_f, out_size, 1000.f);
        return;
    }

    const float* inputs = (const float*)d_in[0];
    const float* hidden = (const float*)d_in[1];
    const int*   ids    = (const int*)d_in[2];
    const float* fc1_w  = (const float*)d_in[3];
    const float* fc1_b  = (const float*)d_in[4];
    const float* fc1_al = (const float*)d_in[5];
    const float* wih    = (const float*)d_in[6];
    const float* whh    = (const float*)d_in[7];
    const float* bih    = (const float*)d_in[8];
    const float* bhh    = (const float*)d_in[9];
    const float* fc2_w  = (const float*)d_in[10];
    const float* fc2_b  = (const float*)d_in[11];
    const float* fc2_al = (const float*)d_in[12];
    const float* fc3_w  = (const float*)d_in[13];
    const float* fc3_b  = (const float*)d_in[14];
    const float* fc3_al = (const float*)d_in[15];
    const float* fc4_w  = (const float*)d_in[16];
    const float* fc4_b  = (const float*)d_in[17];
    const float* fc4_al = (const float*)d_in[18];

    sort_prepw<<<SPW_BLOCKS, 1024, 0, stream>>>(
        ids, perm, seg, ttab, tcount,
        fc1_al, fc1_w, wm1, fc2_al, fc2_w, wm2, fc3_al, fc3_w, wm3,
        fc4_al, fc4_w, wm4, wih, wihp, whh, whhp);

    dim3 blk(256);
    gemm_fc1<<<dim3(136 + 256, 8), blk, 0, stream>>>(
        inputs, wm1, PACKSZ(H, E), fc1_b, y1, H, ttab, tcount,
        perm, hidden, hid_pos, H);
    gru_fused<<<dim3(N / 128, H / 64), dim3(512), 0, stream>>>(
        y1, hid_pos, hidden, wihp, whhp, bih, bhh, perm, out_h, hp, N, H);
    gemm_tiled<ushort_t><<<dim3(136, H / BN), blk, 0, stream>>>(
        hp, H, wm2, PACKSZ(H, H), fc2_b, q2, H, ttab, tcount,
        nullptr, H, H, 1);
    gemm_tiled<ushort_t><<<dim3(136, H / BN), blk, 0, stream>>>(
        q2, H, wm3, PACKSZ(H, H), fc3_b, q3, H, ttab, tcount,
        nullptr, H, H, 1);
    gemm_tiled<float><<<dim3(136, 1), blk, 0, stream>>>(
        q3, H, wm4, PACKSZ(NA, H), fc4_b, out_q, NA, ttab, tcount,
        perm, NA, H, 0);
}